// Round 1
// baseline (77.787 us; speedup 1.0000x reference)
//
#include <hip/hip_runtime.h>
#include <hip/hip_bf16.h>

// ColorHistogramLoss: soft histogram (Gaussian kernel, 64 bins) over
// pred/target (4,3,256,256) fp32, normalized, cumsum, mean |cdf diff|.
//
// Structure:
//   zero_ws     : zero 24*64-float histogram scratch in d_ws
//   hist_kernel : 768 blocks x 256 thr; per-lane 64 register accumulators,
//                 wave butterfly transpose-reduce, LDS combine, global atomics
//   final_kernel: 1 block x 768 thr (12 waves); per-wave scan -> cdf -> |diff|
//                 -> mean scalar to d_out[0]

#define BINS 64
#define NCH 12            // B*C = 4*3
#define HW 65536          // 256*256
#define BPC 32            // pixel-chunks (blocks) per channel-image
#define PIX_PER_BLOCK (HW / BPC)              // 2048
#define THREADS 256
#define PIX_PER_THREAD (PIX_PER_BLOCK / THREADS)  // 8

__device__ __forceinline__ float fast_exp2(float x) {
#if __has_builtin(__builtin_amdgcn_exp2f)
    return __builtin_amdgcn_exp2f(x);   // v_exp_f32
#else
    return exp2f(x);
#endif
}

__global__ void zero_ws(float* ws, int n) {
    int i = blockIdx.x * blockDim.x + threadIdx.x;
    if (i < n) ws[i] = 0.0f;
}

// weight = exp(-d^2/2), d = x*64 - (j+0.5)  (distance in bin units, sigma = 1 bin)
//        = exp2(-(d*S)^2), S = sqrt(log2(e)/2)
__global__ __launch_bounds__(THREADS) void hist_kernel(
        const float* __restrict__ pred,
        const float* __restrict__ target,
        float* __restrict__ hist) {
    const int blk   = blockIdx.x;
    const int ch    = blk / BPC;        // 0..23 (0..11 pred, 12..23 target)
    const int chunk = blk % BPC;
    const float* src = (ch < NCH) ? (pred + (size_t)ch * HW)
                                  : (target + (size_t)(ch - NCH) * HW);
    const int base = chunk * PIX_PER_BLOCK + threadIdx.x;

    const float S  = 0.84932180028801904f;   // sqrt(log2(e)/2)
    const float XS = 64.0f * S;

    float acc[BINS];
    #pragma unroll
    for (int j = 0; j < BINS; ++j) acc[j] = 0.0f;

    for (int p = 0; p < PIX_PER_THREAD; ++p) {
        float x  = src[base + p * THREADS];
        float xs = x * XS;
        #pragma unroll
        for (int j = 0; j < BINS; ++j) {
            float u = xs - (j + 0.5f) * S;   // fold per-bin constant at compile time
            acc[j] += fast_exp2(-(u * u));
        }
    }

    // Butterfly transpose-reduce across the wave:
    // after this, lane l holds sum over all 64 lanes of acc[l] (bin l partial).
    const int lane = threadIdx.x & 63;
    #pragma unroll
    for (int k = 32; k >= 1; k >>= 1) {
        const bool hi = (lane & k) != 0;
        #pragma unroll
        for (int i = 0; i < k; ++i) {
            float keepv = hi ? acc[i + k] : acc[i];
            float sendv = hi ? acc[i] : acc[i + k];
            acc[i] = keepv + __shfl_xor(sendv, k, 64);
        }
    }
    float wave_sum = acc[0];   // partial histogram value for bin `lane`

    // Combine 4 waves of the block in LDS, then one global atomic per bin.
    __shared__ float bh[BINS];
    if (threadIdx.x < BINS) bh[threadIdx.x] = 0.0f;
    __syncthreads();
    atomicAdd(&bh[lane], wave_sum);      // 64 distinct addrs per wave -> no serialize
    __syncthreads();
    if (threadIdx.x < BINS)
        atomicAdd(&hist[ch * BINS + threadIdx.x], bh[threadIdx.x]);
}

__global__ __launch_bounds__(NCH * 64) void final_kernel(
        const float* __restrict__ hist, float* __restrict__ out) {
    const int w    = threadIdx.x >> 6;   // 0..11 -> (b,c) channel
    const int lane = threadIdx.x & 63;   // bin

    float ph = hist[w * BINS + lane];
    float th = hist[(NCH + w) * BINS + lane];

    // inclusive scan over bins (wave64 shfl_up)
    float ps = ph, ts = th;
    #pragma unroll
    for (int d = 1; d < 64; d <<= 1) {
        float a = __shfl_up(ps, d, 64);
        float b = __shfl_up(ts, d, 64);
        if (lane >= d) { ps += a; ts += b; }
    }
    float ptot = __shfl(ps, 63, 64);
    float ttot = __shfl(ts, 63, 64);
    float pc = ps / (ptot + 1e-8f);
    float tc = ts / (ttot + 1e-8f);
    float dv = fabsf(pc - tc);

    // wave reduce
    #pragma unroll
    for (int k = 32; k >= 1; k >>= 1) dv += __shfl_xor(dv, k, 64);

    __shared__ float warr[NCH];
    if (lane == 0) warr[w] = dv;
    __syncthreads();
    if (threadIdx.x == 0) {
        float s = 0.0f;
        #pragma unroll
        for (int i = 0; i < NCH; ++i) s += warr[i];
        out[0] = s / (float)(NCH * BINS);
    }
}

extern "C" void kernel_launch(void* const* d_in, const int* in_sizes, int n_in,
                              void* d_out, int out_size, void* d_ws, size_t ws_size,
                              hipStream_t stream) {
    const float* pred   = (const float*)d_in[0];
    const float* target = (const float*)d_in[1];
    float* hist = (float*)d_ws;          // 2*NCH*BINS = 1536 floats
    float* out  = (float*)d_out;

    zero_ws<<<dim3((2 * NCH * BINS + 255) / 256), dim3(256), 0, stream>>>(
        hist, 2 * NCH * BINS);
    hist_kernel<<<dim3(2 * NCH * BPC), dim3(THREADS), 0, stream>>>(
        pred, target, hist);
    final_kernel<<<dim3(1), dim3(NCH * 64), 0, stream>>>(hist, out);
}